// Round 3
// baseline (1015.936 us; speedup 1.0000x reference)
//
#include <hip/hip_runtime.h>

typedef short bf16x8 __attribute__((ext_vector_type(8)));
typedef float f32x4 __attribute__((ext_vector_type(4)));

#define MAX_C 400000
#define SBAR() __builtin_amdgcn_sched_barrier(0)

// Module-static device scratch (BSS; zero-initialized at module load).
__device__ __align__(16) unsigned short g_W1t[128 * 384];                  // W1^T bf16 [n=128][k=384]
__device__ __align__(16) unsigned short g_W2t[128 * 128];                  // W2^T bf16 [n=128][k=128]
__device__ __align__(16) unsigned short g_cell[((size_t)MAX_C + 1) * 128]; // cell_attr bf16; row MAX_C stays ZERO (mask row)

__device__ __forceinline__ unsigned short f2bf(float f) {
    union { unsigned int i; float f; } v; v.f = f;
    return (unsigned short)((v.i + 0x7FFFu + ((v.i >> 16) & 1u)) >> 16);
}

// -------- Phase 1: cell_attr[c] = sum_{j<3} node_attr[cells_node[3c+j]] -----
// 4 lanes/cell, lane owns 32 floats. ALL 24 gather float4 loads are issued
// before any accumulate (sched_barrier fence) -> 24 loads in flight per lane
// group, 384 lines per wave (2x round-2). Stores: lane writes 64B = one full
// line. f32 accumulate + RNE round -> bit-identical numerics.
__global__ __launch_bounds__(256) void cell_kernel(
        const float* __restrict__ node_attr,
        const int* __restrict__ cells_node, int C)
{
    int t = threadIdx.x;
    int cell = blockIdx.x * 64 + (t >> 2);
    int sub = t & 3;
    if (cell >= C) return;
    int j0 = cells_node[cell * 3 + 0];
    int j1 = cells_node[cell * 3 + 1];
    int j2 = cells_node[cell * 3 + 2];
    const float* r0 = node_attr + (size_t)j0 * 128 + sub * 32;
    const float* r1 = node_attr + (size_t)j1 * 128 + sub * 32;
    const float* r2 = node_attr + (size_t)j2 * 128 + sub * 32;

    float4 v0[8], v1[8], v2[8];
    #pragma unroll
    for (int i = 0; i < 8; ++i) v0[i] = *(const float4*)(r0 + i * 4);
    #pragma unroll
    for (int i = 0; i < 8; ++i) v1[i] = *(const float4*)(r1 + i * 4);
    #pragma unroll
    for (int i = 0; i < 8; ++i) v2[i] = *(const float4*)(r2 + i * 4);
    SBAR();   // keep all 24 loads issued before any accumulate

    unsigned short* dst = g_cell + (size_t)cell * 256 / 2 * 2;  // cell*128 shorts
    dst = g_cell + (size_t)cell * 128 + sub * 32;
    #pragma unroll
    for (int h = 0; h < 4; ++h) {
        float4 sA, sB;
        sA.x = v0[2*h].x + v1[2*h].x + v2[2*h].x;
        sA.y = v0[2*h].y + v1[2*h].y + v2[2*h].y;
        sA.z = v0[2*h].z + v1[2*h].z + v2[2*h].z;
        sA.w = v0[2*h].w + v1[2*h].w + v2[2*h].w;
        sB.x = v0[2*h+1].x + v1[2*h+1].x + v2[2*h+1].x;
        sB.y = v0[2*h+1].y + v1[2*h+1].y + v2[2*h+1].y;
        sB.z = v0[2*h+1].z + v1[2*h+1].z + v2[2*h+1].z;
        sB.w = v0[2*h+1].w + v1[2*h+1].w + v2[2*h+1].w;
        uint4 o;
        o.x = (unsigned)f2bf(sA.x) | ((unsigned)f2bf(sA.y) << 16);
        o.y = (unsigned)f2bf(sA.z) | ((unsigned)f2bf(sA.w) << 16);
        o.z = (unsigned)f2bf(sB.x) | ((unsigned)f2bf(sB.y) << 16);
        o.w = (unsigned)f2bf(sB.z) | ((unsigned)f2bf(sB.w) << 16);
        *(uint4*)(dst + h * 8) = o;
    }
}

// -------- Weight prep: W1 f32 [384][128] -> bf16 W1t [128][384]; W2 same ----
__global__ __launch_bounds__(256) void wprep_kernel(
        const float* __restrict__ W1,
        const float* __restrict__ W2)
{
    int i = blockIdx.x * 256 + threadIdx.x;   // grid covers 49152 + 16384
    if (i < 384 * 128) {
        int n = i / 384, k = i % 384;
        g_W1t[i] = f2bf(W1[k * 128 + n]);
    } else {
        int j = i - 384 * 128;
        int n = j / 128, k = j % 128;
        g_W2t[j] = f2bf(W2[k * 128 + n]);
    }
}

// -------- Edge MLP: D = W^T * X^T, wave owns 32 EDGES x 128 features --------
// Round-2 post-mortem: VGPR=76 proved the compiler collapsed the rotating
// prefetch -> only 2 gathers in flight/wave -> 1.43 TB/s latency-bound.
// This version PINS the pipeline with sched_barrier(0) fences:
//   * sender+receiver B-frags (16 loads, 64 VGPR) + edge chunks 0,1 preloaded
//     up front; edge chunks 2,3 issued mid-loop after sender regs die.
//   * weight A-frags double-buffered one chunk ahead (W1t is L2-resident).
//   * every k-chunk is its own sched region -> loads cannot sink/hoist.
// Peak live ~240 VGPR -> __launch_bounds__(256,2). Wave-private Hs, 0 barriers.
__global__ __launch_bounds__(256, 2) void edge_mlp_kernel(
        const float* __restrict__ edge_attr,
        const float* __restrict__ b1,
        const float* __restrict__ b2,
        const int* __restrict__ senders,
        const int* __restrict__ receivers,
        float* __restrict__ out, int E)
{
    __shared__ __align__(16) unsigned short Hs[128][136];  // [edge][hfeat], 272B rows

    const int t  = threadIdx.x;
    const int wv = t >> 6;
    const int l  = t & 63;
    const int lr = l & 15;   // fragment row/col index
    const int q  = l >> 4;   // k-quad
    const int e0 = blockIdx.x * 128;
    const int eb = e0 + wv * 32;

    const int ei0 = min(eb + lr,      E - 1);
    const int ei1 = min(eb + 16 + lr, E - 1);
    const int s0 = senders[ei0], r0i = receivers[ei0];
    const int s1 = senders[ei1], r1i = receivers[ei1];

    const unsigned qb = (unsigned)(q * 16);
    const unsigned so0 = (unsigned)s0 * 256u + qb;
    const unsigned so1 = (unsigned)s1 * 256u + qb;
    const unsigned ro0 = ((s0 == r0i) ? (unsigned)MAX_C * 256u : (unsigned)r0i * 256u) + qb;
    const unsigned ro1 = ((s1 == r1i) ? (unsigned)MAX_C * 256u : (unsigned)r1i * 256u) + qb;

    const char* cellb = (const char*)g_cell;
    const char* w1b   = (const char*)g_W1t;
    const char* w2b   = (const char*)g_W2t;
    const float* ep0 = edge_attr + (size_t)ei0 * 128 + q * 8;
    const float* ep1 = edge_attr + (size_t)ei1 * 128 + q * 8;

    f32x4 acc[8][2];
    #pragma unroll
    for (int mt = 0; mt < 8; ++mt) { acc[mt][0] = (f32x4)(0.f); acc[mt][1] = (f32x4)(0.f); }

    // ---- B preload: senders (4 chunks x 2 tiles) + receivers + edge c0,c1 --
    bf16x8 sF0[4], sF1[4], rF0[4], rF1[4];
    float4 eL0[4], eH0[4], eL1[4], eH1[4];
    #pragma unroll
    for (int c = 0; c < 4; ++c) {
        sF0[c] = *(const bf16x8*)(cellb + (size_t)(so0 + c * 64));
        sF1[c] = *(const bf16x8*)(cellb + (size_t)(so1 + c * 64));
    }
    #pragma unroll
    for (int c = 0; c < 4; ++c) {
        rF0[c] = *(const bf16x8*)(cellb + (size_t)(ro0 + c * 64));
        rF1[c] = *(const bf16x8*)(cellb + (size_t)(ro1 + c * 64));
    }

    bf16x8 aA[8], aB[8];
    auto loadA1 = [&](bf16x8 (&aD)[8], int kc) {
        #pragma unroll
        for (int mt = 0; mt < 8; ++mt)
            aD[mt] = *(const bf16x8*)(w1b + (size_t)((mt * 16 + lr) * 768 + kc * 64 + qb));
    };
    auto step = [&](bf16x8 bb0, bf16x8 bb1, bf16x8 (&aC)[8]) {
        #pragma unroll
        for (int mt = 0; mt < 8; ++mt) {
            acc[mt][0] = __builtin_amdgcn_mfma_f32_16x16x32_bf16(aC[mt], bb0, acc[mt][0], 0, 0, 0);
            acc[mt][1] = __builtin_amdgcn_mfma_f32_16x16x32_bf16(aC[mt], bb1, acc[mt][1], 0, 0, 0);
        }
    };
    auto cvt = [&](float4 lo, float4 hi) -> bf16x8 {
        union { unsigned short u[8]; bf16x8 v; } r;
        r.u[0] = f2bf(lo.x); r.u[1] = f2bf(lo.y); r.u[2] = f2bf(lo.z); r.u[3] = f2bf(lo.w);
        r.u[4] = f2bf(hi.x); r.u[5] = f2bf(hi.y); r.u[6] = f2bf(hi.z); r.u[7] = f2bf(hi.w);
        return r.v;
    };

    loadA1(aA, 0);
    #pragma unroll
    for (int c = 0; c < 2; ++c) {   // edge chunks 0,1 raw f32
        eL0[c] = *(const float4*)(ep0 + c * 32);
        eH0[c] = *(const float4*)(ep0 + c * 32 + 4);
        eL1[c] = *(const float4*)(ep1 + c * 32);
        eH1[c] = *(const float4*)(ep1 + c * 32 + 4);
    }
    SBAR();
    // kc = 0..3 : senders
    loadA1(aB, 1);  step(sF0[0], sF1[0], aA);  SBAR();
    loadA1(aA, 2);  step(sF0[1], sF1[1], aB);  SBAR();
    loadA1(aB, 3);  step(sF0[2], sF1[2], aA);  SBAR();
    loadA1(aA, 4);  step(sF0[3], sF1[3], aB);  SBAR();
    // kc = 4 : receivers begin; issue edge chunks 2,3 (sender regs now dead)
    loadA1(aB, 5);
    #pragma unroll
    for (int c = 2; c < 4; ++c) {
        eL0[c] = *(const float4*)(ep0 + c * 32);
        eH0[c] = *(const float4*)(ep0 + c * 32 + 4);
        eL1[c] = *(const float4*)(ep1 + c * 32);
        eH1[c] = *(const float4*)(ep1 + c * 32 + 4);
    }
    step(rF0[0], rF1[0], aA);  SBAR();
    loadA1(aA, 6);  step(rF0[1], rF1[1], aB);  SBAR();
    loadA1(aB, 7);  step(rF0[2], rF1[2], aA);  SBAR();
    loadA1(aA, 8);  step(rF0[3], rF1[3], aB);  SBAR();
    // kc = 8..11 : edge_attr (convert f32->bf16 at use)
    loadA1(aB, 9);  step(cvt(eL0[0], eH0[0]), cvt(eL1[0], eH1[0]), aA);  SBAR();
    loadA1(aA, 10); step(cvt(eL0[1], eH0[1]), cvt(eL1[1], eH1[1]), aB);  SBAR();
    loadA1(aB, 11); step(cvt(eL0[2], eH0[2]), cvt(eL1[2], eH1[2]), aA);  SBAR();
    step(cvt(eL0[3], eH0[3]), cvt(eL1[3], eH1[3]), aB);

    // ---- epilogue 1: bias + relu -> Hs (wave-private rows; aligned uint2) --
    #pragma unroll
    for (int mt = 0; mt < 8; ++mt) {
        const int f = mt * 16 + q * 4;
        const float4 bv = *(const float4*)(b1 + f);
        #pragma unroll
        for (int nt = 0; nt < 2; ++nt) {
            float v0 = acc[mt][nt][0] + bv.x; v0 = v0 > 0.f ? v0 : 0.f;
            float v1 = acc[mt][nt][1] + bv.y; v1 = v1 > 0.f ? v1 : 0.f;
            float v2 = acc[mt][nt][2] + bv.z; v2 = v2 > 0.f ? v2 : 0.f;
            float v3 = acc[mt][nt][3] + bv.w; v3 = v3 > 0.f ? v3 : 0.f;
            uint2 w;
            w.x = (unsigned)f2bf(v0) | ((unsigned)f2bf(v1) << 16);
            w.y = (unsigned)f2bf(v2) | ((unsigned)f2bf(v3) << 16);
            *(uint2*)&Hs[wv * 32 + nt * 16 + lr][f] = w;
        }
    }
    // No __syncthreads: Hs rows [wv*32, wv*32+32) are written and read only by
    // wave wv; same-wave LDS ordering is enforced by compiler lgkmcnt.

    // ---- layer 2: K = 128 in 4 chunks; B-frags from wave-private Hs --------
    f32x4 acc2[8][2];
    #pragma unroll
    for (int mt = 0; mt < 8; ++mt) { acc2[mt][0] = (f32x4)(0.f); acc2[mt][1] = (f32x4)(0.f); }

    #pragma unroll
    for (int kc = 0; kc < 4; ++kc) {
        bf16x8 h0 = *(const bf16x8*)&Hs[wv * 32 +      lr][kc * 32 + q * 8];
        bf16x8 h1 = *(const bf16x8*)&Hs[wv * 32 + 16 + lr][kc * 32 + q * 8];
        #pragma unroll
        for (int mt = 0; mt < 8; ++mt) {
            bf16x8 a = *(const bf16x8*)(w2b + (size_t)((mt * 16 + lr) * 256 + kc * 64 + qb));
            acc2[mt][0] = __builtin_amdgcn_mfma_f32_16x16x32_bf16(a, h0, acc2[mt][0], 0, 0, 0);
            acc2[mt][1] = __builtin_amdgcn_mfma_f32_16x16x32_bf16(a, h1, acc2[mt][1], 0, 0, 0);
        }
        SBAR();
    }

    // ---- epilogue 2: bias -> out (float4: 16 edges x one full 64B line) ----
    #pragma unroll
    for (int mt = 0; mt < 8; ++mt) {
        const int f = mt * 16 + q * 4;
        const float4 bv = *(const float4*)(b2 + f);
        #pragma unroll
        for (int nt = 0; nt < 2; ++nt) {
            int e = eb + nt * 16 + lr;
            if (e < E) {
                float4 v;
                v.x = acc2[mt][nt][0] + bv.x;
                v.y = acc2[mt][nt][1] + bv.y;
                v.z = acc2[mt][nt][2] + bv.z;
                v.w = acc2[mt][nt][3] + bv.w;
                *(float4*)(out + (size_t)e * 128 + f) = v;
            }
        }
    }
}

extern "C" void kernel_launch(void* const* d_in, const int* in_sizes, int n_in,
                              void* d_out, int out_size, void* d_ws, size_t ws_size,
                              hipStream_t stream)
{
    const float* node_attr = (const float*)d_in[0];
    const float* edge_attr = (const float*)d_in[1];
    const float* W1 = (const float*)d_in[2];
    const float* b1 = (const float*)d_in[3];
    const float* W2 = (const float*)d_in[4];
    const float* b2 = (const float*)d_in[5];
    const int* cells_node  = (const int*)d_in[6];
    const int* edge_index  = (const int*)d_in[8];
    float* out = (float*)d_out;

    int E = in_sizes[1] / 128;
    int C = in_sizes[6] / 3;

    const int* senders = edge_index;
    const int* receivers = edge_index + E;

    hipLaunchKernelGGL(cell_kernel, dim3((C + 63) / 64), dim3(256), 0, stream,
                       node_attr, cells_node, C);
    hipLaunchKernelGGL(wprep_kernel, dim3(256), dim3(256), 0, stream, W1, W2);
    hipLaunchKernelGGL(edge_mlp_kernel, dim3((E + 127) / 128), dim3(256), 0, stream,
                       edge_attr, b1, b2, senders, receivers, out, E);
}